// Round 10
// baseline (239.776 us; speedup 1.0000x reference)
//
#include <hip/hip_runtime.h>
#include <hip/hip_bf16.h>

#define NAG 256
#define HID 128
#define ACT 5
#define NH 4
#define DD 144      // concat dim
#define EE 576      // embed dim
#define HDIM 144    // per-head dim
#define CMAX 20     // fast-path neighbor cap (expected c ~ 4-8)

// ---------------------------------------------------------------------------
// gemm1 (fused prep): per block = (bx,z,mb) via XCD swizzle.
//   C-tile[16 x 144] = concat(enc(hidden rows), action rows)  (in LDS)
//   out[16 x 64cols] = C-tile @ W{q,k,v}[:, bx*64..] + b
// grid 512 x 256 thr. Swizzle: xcd=p%8, so all mb of one (bx,z) share an XCD
// -> the 147KB W strip stays in that XCD's L2 (fixes 5-6x HBM overfetch).
// ---------------------------------------------------------------------------
__global__ __launch_bounds__(256) void k_gemm1(
    const float* __restrict__ hidden, const float* __restrict__ action,
    const float* __restrict__ W_enc, const float* __restrict__ b_enc,
    const float* __restrict__ Wq, const float* __restrict__ Wk, const float* __restrict__ Wv,
    const float* __restrict__ bq, const float* __restrict__ bk, const float* __restrict__ bv,
    float* __restrict__ tq, float* __restrict__ tk, float* __restrict__ tv)
{
    const int p = blockIdx.x;
    const int xcd = p & 7, qq = p >> 3;
    const int gslot = qq >> 4, mb = qq & 15;
    const int g = xcd + 8 * gslot;          // block-uniform
    if (g >= 27) return;                    // before any barrier: safe
    const int bx = g % 9, z = g / 9;
    const float* W  = (z == 0) ? Wq : (z == 1) ? Wk : Wv;
    const float* bi = (z == 0) ? bq : (z == 1) ? bk : bv;
    float*      out = (z == 0) ? tq : (z == 1) ? tk : tv;

    __shared__ float Hs[16][HID + 4];       // pad: stride 132
    __shared__ float As[16][DD + 4];        // stride 148
    const int tid = threadIdx.x;
    {
        const float4* Hf = (const float4*)(hidden + mb * 16 * HID);
        const float4* Af = (const float4*)(action + mb * 16 * HID);
        for (int idx = tid; idx < 16 * HID / 4; idx += 256) {
            int lin = idx * 4, rr = lin >> 7, kk = lin & 127;
            *((float4*)&Hs[rr][kk]) = Hf[idx];
            *((float4*)&As[rr][16 + kk]) = Af[idx];
        }
    }
    __syncthreads();
    {   // enc: 16 rows x 16 outs, one task per thread
        int r = tid >> 4, o = tid & 15;
        float acc = 0.f;
        for (int d = 0; d < HID; ++d) acc += Hs[r][d] * W_enc[d * 16 + o];
        As[r][o] = acc + b_enc[o];
    }
    __syncthreads();
    const int r = tid >> 4;
    const int col = bx * 64 + (tid & 15) * 4;
    const float* Ar = As[r];
    const float* Wc = W + col;
    float ac0 = 0.f, ac1 = 0.f, ac2 = 0.f, ac3 = 0.f;
    #pragma unroll 8
    for (int k = 0; k < DD; ++k) {
        float a = Ar[k];
        float4 w4 = *(const float4*)(Wc + (size_t)k * EE);
        ac0 += a * w4.x; ac1 += a * w4.y; ac2 += a * w4.z; ac3 += a * w4.w;
    }
    const int row = mb * 16 + r;
    float4 o4 = { ac0 + bi[col], ac1 + bi[col + 1], ac2 + bi[col + 2], ac3 + bi[col + 3] };
    *((float4*)(out + (size_t)row * EE + col)) = o4;
}

// ---------------------------------------------------------------------------
// General swizzled GEMM: out[z] = A[z] @ W[z] (+ bscale[row]*b[z]).
// K template; G groups = NX * NZ; grid = 8*ceil(G/8)*16 blocks of 256.
// ---------------------------------------------------------------------------
template<int K, int NX, int G>
__global__ __launch_bounds__(256) void k_gemmN(
    const float* __restrict__ A0, const float* __restrict__ A1, const float* __restrict__ A2,
    const float* __restrict__ W0, const float* __restrict__ W1, const float* __restrict__ W2,
    const float* __restrict__ bb0, const float* __restrict__ bb1, const float* __restrict__ bb2,
    const float* __restrict__ bscale,
    float* __restrict__ o0, float* __restrict__ o1, float* __restrict__ o2,
    int N)
{
    const int p = blockIdx.x;
    const int xcd = p & 7, qq = p >> 3;
    const int gslot = qq >> 4, mb = qq & 15;
    const int g = xcd + 8 * gslot;          // block-uniform
    if (g >= G) return;                     // before any barrier
    const int bx = g % NX, z = g / NX;

    constexpr int LDA = K + 4;
    __shared__ float As[16 * LDA];
    const float* A   = (z == 0) ? A0  : (z == 1) ? A1  : A2;
    const float* W   = (z == 0) ? W0  : (z == 1) ? W1  : W2;
    const float* bia = (z == 0) ? bb0 : (z == 1) ? bb1 : bb2;
    float*       out = (z == 0) ? o0  : (z == 1) ? o1  : o2;
    const int tid = threadIdx.x;
    {
        const float4* Af = (const float4*)(A + (size_t)mb * 16 * K);
        for (int idx = tid; idx < 16 * K / 4; idx += 256) {
            float4 v4 = Af[idx];
            int lin = idx * 4;
            int rr = lin / K, kk = lin - rr * K;   // K%4==0: no row crossing
            *((float4*)&As[rr * LDA + kk]) = v4;
        }
    }
    __syncthreads();
    const int r = tid >> 4;
    const int col = bx * 64 + (tid & 15) * 4;
    if (col >= N) return;                          // after last barrier
    const float* Ar = &As[r * LDA];
    const float* Wc = W + col;
    float ac0 = 0.f, ac1 = 0.f, ac2 = 0.f, ac3 = 0.f;
    #pragma unroll 8
    for (int k = 0; k < K; ++k) {
        float a = Ar[k];
        float4 w4 = *(const float4*)(Wc + (size_t)k * N);
        ac0 += a * w4.x; ac1 += a * w4.y; ac2 += a * w4.z; ac3 += a * w4.w;
    }
    const int row = mb * 16 + r;
    float bs = bscale ? bscale[row] : 1.f;
    float4 o4;
    o4.x = ac0 + (bia ? bs * bia[col + 0] : 0.f);
    o4.y = ac1 + (bia ? bs * bia[col + 1] : 0.f);
    o4.z = ac2 + (bia ? bs * bia[col + 2] : 0.f);
    o4.w = ac3 + (bia ? bs * bia[col + 3] : 0.f);
    *((float4*)(out + (size_t)row * N + col)) = o4;
}

// ---------------------------------------------------------------------------
// Fused scores + attention reduction. Per agent i (block):
//  1. neighbor list M_i (c = |M_i|)
//  2. fast path (c<=CMAX): per head h, stage q/k neighbor rows in LDS,
//     compute c x c scores, softmax rows serially in registers, column-sum
//     -> w[h][kk].
//  3. ctxsum[i,e] = sum_t w[h(e)][t] * v[lst[t],e];  cnt[i]=c.
// ---------------------------------------------------------------------------
__global__ __launch_bounds__(256) void k_attn(
    const int* __restrict__ state, const float* __restrict__ q,
    const float* __restrict__ kmat, const float* __restrict__ v,
    float* __restrict__ ctxsum, float* __restrict__ cnt)
{
    __shared__ int lst[NAG];
    __shared__ int cnt_s;
    __shared__ float w4[NH][NAG];
    __shared__ float qh[CMAX][HDIM + 1];   // pad: odd stride
    __shared__ float kh[CMAX][HDIM + 1];
    __shared__ float Sl[CMAX][CMAX + 1];
    const int i = blockIdx.x, tid = threadIdx.x;
    if (tid == 0) cnt_s = 0;
    __syncthreads();
    {
        int xi = state[2 * i], yi = state[2 * i + 1];
        int xj = state[2 * tid], yj = state[2 * tid + 1];
        int dx = xi - xj; if (dx < 0) dx = -dx;
        int dy = yi - yj; if (dy < 0) dy = -dy;
        if (tid > i && dx <= 4 && dy <= 2) {
            int p = atomicAdd(&cnt_s, 1);
            lst[p] = tid;
        }
    }
    __syncthreads();
    const int c = cnt_s;                 // block-uniform
    if (tid == 0) cnt[i] = (float)c;
    if (c == 0) {
        for (int e = tid; e < EE; e += 256) ctxsum[i * EE + e] = 0.f;
        return;
    }
    if (c <= CMAX) {
        for (int h = 0; h < NH; ++h) {
            for (int idx = tid; idx < c * HDIM; idx += 256) {
                int jj = idx / HDIM, d = idx % HDIM;
                qh[jj][d] = q[lst[jj] * EE + h * HDIM + d];
                kh[jj][d] = kmat[lst[jj] * EE + h * HDIM + d];
            }
            __syncthreads();
            for (int pp = tid; pp < c * c; pp += 256) {
                int jj = pp / c, kk = pp % c;
                float acc = 0.f;
                for (int d = 0; d < HDIM; ++d) acc += qh[jj][d] * kh[kk][d];
                Sl[jj][kk] = acc * (1.0f / 12.0f);
            }
            __syncthreads();
            if (tid < c) {               // softmax of row tid, serial (c small)
                float m = -1e30f;
                for (int kk = 0; kk < c; ++kk) m = fmaxf(m, Sl[tid][kk]);
                float zz = 0.f;
                for (int kk = 0; kk < c; ++kk) zz += __expf(Sl[tid][kk] - m);
                float inv = 1.f / fmaxf(zz, 1e-9f);
                for (int kk = 0; kk < c; ++kk)
                    Sl[tid][kk] = __expf(Sl[tid][kk] - m) * inv;
            }
            __syncthreads();
            if (tid < c) {               // column sum -> w
                float s = 0.f;
                for (int jj = 0; jj < c; ++jj) s += Sl[jj][tid];
                w4[h][tid] = s;
            }
            __syncthreads();             // qh/Sl reused next head
        }
    } else {
        // fallback c > CMAX: 3-pass recompute from global q/k (rare)
        for (int idx = tid; idx < NH * c; idx += 256) w4[idx / c][idx % c] = 0.f;
        __syncthreads();
        for (int pnh = tid; pnh < NH * c; pnh += 256) {
            int h = pnh / c, jj = pnh % c;
            const float* qrow = q + lst[jj] * EE + h * HDIM;
            float m = -1e30f;
            for (int kk = 0; kk < c; ++kk) {
                const float* krow = kmat + lst[kk] * EE + h * HDIM;
                float a = 0.f;
                for (int d = 0; d < HDIM; ++d) a += qrow[d] * krow[d];
                m = fmaxf(m, a * (1.0f / 12.0f));
            }
            float zz = 0.f;
            for (int kk = 0; kk < c; ++kk) {
                const float* krow = kmat + lst[kk] * EE + h * HDIM;
                float a = 0.f;
                for (int d = 0; d < HDIM; ++d) a += qrow[d] * krow[d];
                zz += __expf(a * (1.0f / 12.0f) - m);
            }
            float inv = 1.f / fmaxf(zz, 1e-9f);
            for (int kk = 0; kk < c; ++kk) {
                const float* krow = kmat + lst[kk] * EE + h * HDIM;
                float a = 0.f;
                for (int d = 0; d < HDIM; ++d) a += qrow[d] * krow[d];
                atomicAdd(&w4[h][kk], __expf(a * (1.0f / 12.0f) - m) * inv);
            }
        }
        __syncthreads();
    }
    for (int e = tid; e < EE; e += 256) {
        int h = e / HDIM;
        float acc = 0.f;
        for (int t = 0; t < c; ++t) acc += w4[h][t] * v[lst[t] * EE + e];
        ctxsum[i * EE + e] = acc;
    }
}

// ---------------------------------------------------------------------------
// Dueling head: per agent i (block, 64 threads).
// ---------------------------------------------------------------------------
__global__ __launch_bounds__(64) void k_head(
    const float* __restrict__ h,
    const float* __restrict__ W_val, const float* __restrict__ b_val,
    const float* __restrict__ W_adv, const float* __restrict__ b_adv,
    float* __restrict__ out)
{
    const int i = blockIdx.x, t = threadIdx.x;
    const float* hr = h + i * DD;
    float h0 = hr[t], h1 = hr[t + 64];
    float h2 = (t < 16) ? hr[t + 128] : 0.f;
    float red[6];
    for (int o = 0; o < 6; ++o) {
        float p;
        if (o < 5) {
            p = h0 * W_adv[t * ACT + o] + h1 * W_adv[(t + 64) * ACT + o];
            if (t < 16) p += h2 * W_adv[(t + 128) * ACT + o];
        } else {
            p = h0 * W_val[t] + h1 * W_val[t + 64];
            if (t < 16) p += h2 * W_val[t + 128];
        }
        for (int off = 32; off; off >>= 1) p += __shfl_xor(p, off);
        red[o] = p;
    }
    if (t == 0) {
        float a[ACT], mean = 0.f;
        for (int o = 0; o < ACT; ++o) { a[o] = red[o] + b_adv[o]; mean += a[o]; }
        mean *= (1.0f / ACT);
        float V = red[5] + b_val[0];
        for (int o = 0; o < ACT; ++o) out[i * ACT + o] = V + a[o] - mean;
    }
}

// ---------------------------------------------------------------------------
extern "C" void kernel_launch(void* const* d_in, const int* in_sizes, int n_in,
                              void* d_out, int out_size, void* d_ws, size_t ws_size,
                              hipStream_t stream)
{
    const float* hidden = (const float*)d_in[0];
    const float* action = (const float*)d_in[1];
    const int*   state  = (const int*)d_in[2];

    float* ws = (float*)d_ws;
    float* tq   = ws;                        // 256*576 each
    float* tk   = tq  + NAG * EE;
    float* tv   = tk  + NAG * EE;
    float* q    = tv  + NAG * EE;
    float* kbuf = q   + NAG * EE;
    float* v    = kbuf+ NAG * EE;
    float* ctx  = v   + NAG * EE;            // attn reads q/kbuf/v -> no alias
    float* cnt  = ctx + NAG * EE;            // 256
    // aliases: tq,tk dead after gemm2
    float* tout = tq;
    float* hbuf = tk;
    // total ws use ~4.13 MB (round-8 proven capacity ~4.2 MB)

    // gemm1 (fused enc): t_{q,k,v} = concat(enc(hidden),action) @ {Wq,Wk,Wv}+b
    k_gemm1<<<512, 256, 0, stream>>>(hidden, action,
        (const float*)d_in[3], (const float*)d_in[4],
        (const float*)d_in[5], (const float*)d_in[7], (const float*)d_in[9],
        (const float*)d_in[6], (const float*)d_in[8], (const float*)d_in[10],
        tq, tk, tv);

    // gemm2: {q,k,v} = t @ {Wiq,Wik,Wiv} + bi   (K=576, N=576, G=27)
    k_gemmN<576, 9, 27><<<512, 256, 0, stream>>>(tq, tk, tv,
        (const float*)d_in[11], (const float*)d_in[13], (const float*)d_in[15],
        (const float*)d_in[12], (const float*)d_in[14], (const float*)d_in[16],
        nullptr, q, kbuf, v, EE);

    // fused scores+attention
    k_attn<<<NAG, 256, 0, stream>>>(state, q, kbuf, v, ctx, cnt);

    // gemm3: tout = ctx @ Wo + cnt*bo   (K=576, N=576, G=9)
    k_gemmN<576, 9, 9><<<256, 256, 0, stream>>>(ctx, ctx, ctx,
        (const float*)d_in[17], (const float*)d_in[17], (const float*)d_in[17],
        (const float*)d_in[18], (const float*)d_in[18], (const float*)d_in[18],
        cnt, tout, tout, tout, EE);

    // gemm4: hbuf = tout @ W_O   (K=576, N=144, G=3, no bias)
    k_gemmN<576, 3, 3><<<128, 256, 0, stream>>>(tout, tout, tout,
        (const float*)d_in[19], (const float*)d_in[19], (const float*)d_in[19],
        nullptr, nullptr, nullptr,
        nullptr, hbuf, hbuf, hbuf, DD);

    k_head<<<NAG, 64, 0, stream>>>(hbuf,
        (const float*)d_in[20], (const float*)d_in[21],
        (const float*)d_in[22], (const float*)d_in[23], (float*)d_out);
}

// Round 11
// 224.477 us; speedup vs baseline: 1.0682x; 1.0682x over previous
//
#include <hip/hip_runtime.h>
#include <hip/hip_bf16.h>

#define NAG 256
#define HID 128
#define ACT 5
#define NH 4
#define DD 144      // concat dim
#define EE 576      // embed dim
#define HDIM 144    // per-head dim
#define CMAX 20     // fast-path neighbor cap (expected c ~ 4-8)

// ---------------------------------------------------------------------------
// gemm1 (fused prep): per block = (bx,z,mb) via XCD swizzle.
//   C-tile[16 x 144] = concat(enc(hidden rows), action rows)  (in LDS)
//   out[16 x 64cols] = C-tile @ W{q,k,v}[:, bx*64..] + b
// ---------------------------------------------------------------------------
__global__ __launch_bounds__(256) void k_gemm1(
    const float* __restrict__ hidden, const float* __restrict__ action,
    const float* __restrict__ W_enc, const float* __restrict__ b_enc,
    const float* __restrict__ Wq, const float* __restrict__ Wk, const float* __restrict__ Wv,
    const float* __restrict__ bq, const float* __restrict__ bk, const float* __restrict__ bv,
    float* __restrict__ tq, float* __restrict__ tk, float* __restrict__ tv)
{
    const int p = blockIdx.x;
    const int xcd = p & 7, qq = p >> 3;
    const int gslot = qq >> 4, mb = qq & 15;
    const int g = xcd + 8 * gslot;          // block-uniform
    if (g >= 27) return;                    // before any barrier: safe
    const int bx = g % 9, z = g / 9;
    const float* W  = (z == 0) ? Wq : (z == 1) ? Wk : Wv;
    const float* bi = (z == 0) ? bq : (z == 1) ? bk : bv;
    float*      out = (z == 0) ? tq : (z == 1) ? tk : tv;

    __shared__ float Hs[16][HID + 4];
    __shared__ float As[16][DD + 4];
    const int tid = threadIdx.x;
    {
        const float4* Hf = (const float4*)(hidden + mb * 16 * HID);
        const float4* Af = (const float4*)(action + mb * 16 * HID);
        for (int idx = tid; idx < 16 * HID / 4; idx += 256) {
            int lin = idx * 4, rr = lin >> 7, kk = lin & 127;
            *((float4*)&Hs[rr][kk]) = Hf[idx];
            *((float4*)&As[rr][16 + kk]) = Af[idx];
        }
    }
    __syncthreads();
    {   // enc: 16 rows x 16 outs, one task per thread
        int r = tid >> 4, o = tid & 15;
        float acc = 0.f;
        for (int d = 0; d < HID; ++d) acc += Hs[r][d] * W_enc[d * 16 + o];
        As[r][o] = acc + b_enc[o];
    }
    __syncthreads();
    const int r = tid >> 4;
    const int col = bx * 64 + (tid & 15) * 4;
    const float* Ar = As[r];
    const float* Wc = W + col;
    float ac0 = 0.f, ac1 = 0.f, ac2 = 0.f, ac3 = 0.f;
    #pragma unroll 8
    for (int k = 0; k < DD; ++k) {
        float a = Ar[k];
        float4 w4 = *(const float4*)(Wc + (size_t)k * EE);
        ac0 += a * w4.x; ac1 += a * w4.y; ac2 += a * w4.z; ac3 += a * w4.w;
    }
    const int row = mb * 16 + r;
    float4 o4 = { ac0 + bi[col], ac1 + bi[col + 1], ac2 + bi[col + 2], ac3 + bi[col + 3] };
    *((float4*)(out + (size_t)row * EE + col)) = o4;
}

// ---------------------------------------------------------------------------
// Split-K swizzled GEMM: out[z] = A[z] @ W[z] (+ bscale[row]*b[z]).
// KS=2 K-chunks: ks0 writes out (with bias), ks1 writes pbuf; reduce adds.
// Shorter dependent-load chain (Kc/8 batches) + 2x blocks = latency hidden.
// grid = 8 * 32 * ceil(G/8); decode: xcd|inner(mb,ks)|gslot.
// ---------------------------------------------------------------------------
template<int K, int KS, int NX, int G>
__global__ __launch_bounds__(256) void k_gemmS(
    const float* __restrict__ A0, const float* __restrict__ A1, const float* __restrict__ A2,
    const float* __restrict__ W0, const float* __restrict__ W1, const float* __restrict__ W2,
    const float* __restrict__ bb0, const float* __restrict__ bb1, const float* __restrict__ bb2,
    const float* __restrict__ bscale,
    float* __restrict__ o0, float* __restrict__ o1, float* __restrict__ o2,
    float* __restrict__ pbuf, int N)
{
    constexpr int Kc = K / KS;
    constexpr int LDA = Kc + 4;
    const int p = blockIdx.x;
    const int xcd = p & 7, t = p >> 3;
    const int inner = t & 31, gslot = t >> 5;
    const int g = xcd + 8 * gslot;          // block-uniform
    if (g >= G) return;                     // before any barrier
    const int mb = inner & 15, ks = inner >> 4;
    const int bx = g % NX, z = g / NX;
    const int k0 = ks * Kc;

    __shared__ float As[16 * LDA];
    const float* A   = (z == 0) ? A0  : (z == 1) ? A1  : A2;
    const float* W   = (z == 0) ? W0  : (z == 1) ? W1  : W2;
    const float* bia = (z == 0) ? bb0 : (z == 1) ? bb1 : bb2;
    float*       out = (z == 0) ? o0  : (z == 1) ? o1  : o2;
    const int tid = threadIdx.x;
    {   // stage A tile rows [mb*16, +16), cols [k0, k0+Kc)
        for (int idx = tid; idx < 16 * (Kc / 4); idx += 256) {
            int rr = idx / (Kc / 4), kq = idx % (Kc / 4);
            float4 v4 = *(const float4*)(A + (size_t)(mb * 16 + rr) * K + k0 + 4 * kq);
            *((float4*)&As[rr * LDA + 4 * kq]) = v4;
        }
    }
    __syncthreads();
    const int r = tid >> 4;
    const int col = bx * 64 + (tid & 15) * 4;
    if (col >= N) return;                          // after last barrier
    const float* Ar = &As[r * LDA];
    const float* Wc = W + (size_t)k0 * N + col;
    float ac0 = 0.f, ac1 = 0.f, ac2 = 0.f, ac3 = 0.f;
    #pragma unroll 8
    for (int kk = 0; kk < Kc; ++kk) {
        float a = Ar[kk];
        float4 w4 = *(const float4*)(Wc + (size_t)kk * N);
        ac0 += a * w4.x; ac1 += a * w4.y; ac2 += a * w4.z; ac3 += a * w4.w;
    }
    const int row = mb * 16 + r;
    if (ks == 0) {
        float bs = bscale ? bscale[row] : 1.f;
        float4 o4;
        o4.x = ac0 + (bia ? bs * bia[col + 0] : 0.f);
        o4.y = ac1 + (bia ? bs * bia[col + 1] : 0.f);
        o4.z = ac2 + (bia ? bs * bia[col + 2] : 0.f);
        o4.w = ac3 + (bia ? bs * bia[col + 3] : 0.f);
        *((float4*)(out + (size_t)row * N + col)) = o4;
    } else {
        float4 o4 = { ac0, ac1, ac2, ac3 };
        *((float4*)(pbuf + (size_t)z * NAG * N + (size_t)row * N + col)) = o4;
    }
}

// ---------------------------------------------------------------------------
// Reduce: out[i] += p[i], float4-vectorized. grid = ceil(n4/256).
// ---------------------------------------------------------------------------
__global__ __launch_bounds__(256) void k_add(
    float* __restrict__ out, const float* __restrict__ p, int n4)
{
    int i = blockIdx.x * 256 + threadIdx.x;
    if (i < n4) {
        float4 o = ((float4*)out)[i];
        float4 a = ((const float4*)p)[i];
        o.x += a.x; o.y += a.y; o.z += a.z; o.w += a.w;
        ((float4*)out)[i] = o;
    }
}

// ---------------------------------------------------------------------------
// Fused scores + attention reduction (proven in rounds 8/10).
// ---------------------------------------------------------------------------
__global__ __launch_bounds__(256) void k_attn(
    const int* __restrict__ state, const float* __restrict__ q,
    const float* __restrict__ kmat, const float* __restrict__ v,
    float* __restrict__ ctxsum, float* __restrict__ cnt)
{
    __shared__ int lst[NAG];
    __shared__ int cnt_s;
    __shared__ float w4[NH][NAG];
    __shared__ float qh[CMAX][HDIM + 1];
    __shared__ float kh[CMAX][HDIM + 1];
    __shared__ float Sl[CMAX][CMAX + 1];
    const int i = blockIdx.x, tid = threadIdx.x;
    if (tid == 0) cnt_s = 0;
    __syncthreads();
    {
        int xi = state[2 * i], yi = state[2 * i + 1];
        int xj = state[2 * tid], yj = state[2 * tid + 1];
        int dx = xi - xj; if (dx < 0) dx = -dx;
        int dy = yi - yj; if (dy < 0) dy = -dy;
        if (tid > i && dx <= 4 && dy <= 2) {
            int p = atomicAdd(&cnt_s, 1);
            lst[p] = tid;
        }
    }
    __syncthreads();
    const int c = cnt_s;                 // block-uniform
    if (tid == 0) cnt[i] = (float)c;
    if (c == 0) {
        for (int e = tid; e < EE; e += 256) ctxsum[i * EE + e] = 0.f;
        return;
    }
    if (c <= CMAX) {
        for (int h = 0; h < NH; ++h) {
            for (int idx = tid; idx < c * HDIM; idx += 256) {
                int jj = idx / HDIM, d = idx % HDIM;
                qh[jj][d] = q[lst[jj] * EE + h * HDIM + d];
                kh[jj][d] = kmat[lst[jj] * EE + h * HDIM + d];
            }
            __syncthreads();
            for (int pp = tid; pp < c * c; pp += 256) {
                int jj = pp / c, kk = pp % c;
                float acc = 0.f;
                for (int d = 0; d < HDIM; ++d) acc += qh[jj][d] * kh[kk][d];
                Sl[jj][kk] = acc * (1.0f / 12.0f);
            }
            __syncthreads();
            if (tid < c) {
                float m = -1e30f;
                for (int kk = 0; kk < c; ++kk) m = fmaxf(m, Sl[tid][kk]);
                float zz = 0.f;
                for (int kk = 0; kk < c; ++kk) zz += __expf(Sl[tid][kk] - m);
                float inv = 1.f / fmaxf(zz, 1e-9f);
                for (int kk = 0; kk < c; ++kk)
                    Sl[tid][kk] = __expf(Sl[tid][kk] - m) * inv;
            }
            __syncthreads();
            if (tid < c) {
                float s = 0.f;
                for (int jj = 0; jj < c; ++jj) s += Sl[jj][tid];
                w4[h][tid] = s;
            }
            __syncthreads();
        }
    } else {
        for (int idx = tid; idx < NH * c; idx += 256) w4[idx / c][idx % c] = 0.f;
        __syncthreads();
        for (int pnh = tid; pnh < NH * c; pnh += 256) {
            int h = pnh / c, jj = pnh % c;
            const float* qrow = q + lst[jj] * EE + h * HDIM;
            float m = -1e30f;
            for (int kk = 0; kk < c; ++kk) {
                const float* krow = kmat + lst[kk] * EE + h * HDIM;
                float a = 0.f;
                for (int d = 0; d < HDIM; ++d) a += qrow[d] * krow[d];
                m = fmaxf(m, a * (1.0f / 12.0f));
            }
            float zz = 0.f;
            for (int kk = 0; kk < c; ++kk) {
                const float* krow = kmat + lst[kk] * EE + h * HDIM;
                float a = 0.f;
                for (int d = 0; d < HDIM; ++d) a += qrow[d] * krow[d];
                zz += __expf(a * (1.0f / 12.0f) - m);
            }
            float inv = 1.f / fmaxf(zz, 1e-9f);
            for (int kk = 0; kk < c; ++kk) {
                const float* krow = kmat + lst[kk] * EE + h * HDIM;
                float a = 0.f;
                for (int d = 0; d < HDIM; ++d) a += qrow[d] * krow[d];
                atomicAdd(&w4[h][kk], __expf(a * (1.0f / 12.0f) - m) * inv);
            }
        }
        __syncthreads();
    }
    for (int e = tid; e < EE; e += 256) {
        int h = e / HDIM;
        float acc = 0.f;
        for (int t = 0; t < c; ++t) acc += w4[h][t] * v[lst[t] * EE + e];
        ctxsum[i * EE + e] = acc;
    }
}

// ---------------------------------------------------------------------------
// Dueling head: per agent i (block, 64 threads).
// ---------------------------------------------------------------------------
__global__ __launch_bounds__(64) void k_head(
    const float* __restrict__ h,
    const float* __restrict__ W_val, const float* __restrict__ b_val,
    const float* __restrict__ W_adv, const float* __restrict__ b_adv,
    float* __restrict__ out)
{
    const int i = blockIdx.x, t = threadIdx.x;
    const float* hr = h + i * DD;
    float h0 = hr[t], h1 = hr[t + 64];
    float h2 = (t < 16) ? hr[t + 128] : 0.f;
    float red[6];
    for (int o = 0; o < 6; ++o) {
        float p;
        if (o < 5) {
            p = h0 * W_adv[t * ACT + o] + h1 * W_adv[(t + 64) * ACT + o];
            if (t < 16) p += h2 * W_adv[(t + 128) * ACT + o];
        } else {
            p = h0 * W_val[t] + h1 * W_val[t + 64];
            if (t < 16) p += h2 * W_val[t + 128];
        }
        for (int off = 32; off; off >>= 1) p += __shfl_xor(p, off);
        red[o] = p;
    }
    if (t == 0) {
        float a[ACT], mean = 0.f;
        for (int o = 0; o < ACT; ++o) { a[o] = red[o] + b_adv[o]; mean += a[o]; }
        mean *= (1.0f / ACT);
        float V = red[5] + b_val[0];
        for (int o = 0; o < ACT; ++o) out[i * ACT + o] = V + a[o] - mean;
    }
}

// ---------------------------------------------------------------------------
extern "C" void kernel_launch(void* const* d_in, const int* in_sizes, int n_in,
                              void* d_out, int out_size, void* d_ws, size_t ws_size,
                              hipStream_t stream)
{
    const float* hidden = (const float*)d_in[0];
    const float* action = (const float*)d_in[1];
    const int*   state  = (const int*)d_in[2];

    float* ws = (float*)d_ws;
    float* tq   = ws;                        // 256*576 each
    float* tk   = tq  + NAG * EE;
    float* tv   = tk  + NAG * EE;
    float* q    = tv  + NAG * EE;            // q,kbuf,v contiguous (reduce!)
    float* kbuf = q   + NAG * EE;
    float* v    = kbuf+ NAG * EE;
    float* ctx  = v   + NAG * EE;
    float* cnt  = ctx + NAG * EE;            // 256
    float* pbuf = cnt + NAG;                 // 3*256*576 = 442368 (split-K partials)
    // aliases: tq,tk dead after gemm2
    float* tout = tq;
    float* hbuf = tk;
    // total ws use ~5.9 MB

    // gemm1 (fused enc): t_{q,k,v} = concat(enc(hidden),action) @ {Wq,Wk,Wv}+b
    k_gemm1<<<512, 256, 0, stream>>>(hidden, action,
        (const float*)d_in[3], (const float*)d_in[4],
        (const float*)d_in[5], (const float*)d_in[7], (const float*)d_in[9],
        (const float*)d_in[6], (const float*)d_in[8], (const float*)d_in[10],
        tq, tk, tv);

    // gemm2: {q,k,v} = t @ {Wiq,Wik,Wiv} + bi   (K=576 split 2, G=27)
    k_gemmS<576, 2, 9, 27><<<1024, 256, 0, stream>>>(tq, tk, tv,
        (const float*)d_in[11], (const float*)d_in[13], (const float*)d_in[15],
        (const float*)d_in[12], (const float*)d_in[14], (const float*)d_in[16],
        nullptr, q, kbuf, v, pbuf, EE);
    k_add<<<(3 * NAG * EE / 4 + 255) / 256, 256, 0, stream>>>(q, pbuf, 3 * NAG * EE / 4);

    // fused scores+attention
    k_attn<<<NAG, 256, 0, stream>>>(state, q, kbuf, v, ctx, cnt);

    // gemm3: tout = ctx @ Wo + cnt*bo   (K=576 split 2, G=9)
    k_gemmS<576, 2, 9, 9><<<512, 256, 0, stream>>>(ctx, ctx, ctx,
        (const float*)d_in[17], (const float*)d_in[17], (const float*)d_in[17],
        (const float*)d_in[18], (const float*)d_in[18], (const float*)d_in[18],
        cnt, tout, tout, tout, pbuf, EE);
    k_add<<<(NAG * EE / 4 + 255) / 256, 256, 0, stream>>>(tout, pbuf, NAG * EE / 4);

    // gemm4: hbuf = tout @ W_O   (K=576 split 2, G=3, N=144, no bias)
    k_gemmS<576, 2, 3, 3><<<256, 256, 0, stream>>>(tout, tout, tout,
        (const float*)d_in[19], (const float*)d_in[19], (const float*)d_in[19],
        nullptr, nullptr, nullptr,
        nullptr, hbuf, hbuf, hbuf, pbuf, DD);
    k_add<<<(NAG * DD / 4 + 255) / 256, 256, 0, stream>>>(hbuf, pbuf, NAG * DD / 4);

    k_head<<<NAG, 64, 0, stream>>>(hbuf,
        (const float*)d_in[20], (const float*)d_in[21],
        (const float*)d_in[22], (const float*)d_in[23], (float*)d_out);
}